// Round 3
// baseline (147.861 us; speedup 1.0000x reference)
//
#include <hip/hip_runtime.h>

#define N_WORDS   16384
#define L_CHARS   16
#define CHAR_SIZE 128
#define C_EMB     64
#define CONV_L    256
#define KERNEL_K  3
#define D_EMB     300
#define OUT_STRIDE (CONV_L + D_EMB)   // 556
#define T_ROW     (KERNEL_K * CONV_L) // 768 halfs per char

typedef _Float16 half8 __attribute__((ext_vector_type(8)));

static __device__ __forceinline__ half8 h8max(half8 a, half8 b) {
#if __has_builtin(__builtin_elementwise_max)
    return __builtin_elementwise_max(a, b);
#else
    half8 r;
    #pragma unroll
    for (int i = 0; i < 8; ++i) r[i] = a[i] > b[i] ? a[i] : b[i];
    return r;
#endif
}

// ---------------------------------------------------------------------------
// Build the folded table directly from w (O,I,K):
//   Th[c][k][o] = (half) sum_i emb[c][i] * w[o][i][k]
// Grid 384 = (c,k); thread = o. Per-lane reads of w stride 768 B (uncoalesced
// but only 25 MB total, all L2-resident after first touch; 64-deep unroll
// gives the MLP to hide latency). emb reads are wave-uniform (s_load).
__global__ void build_table(const float* __restrict__ emb,
                            const float* __restrict__ w,
                            _Float16* __restrict__ Th) {
    int c = blockIdx.x / 3;
    int k = blockIdx.x % 3;
    int o = threadIdx.x;
    const float* erow = emb + c * C_EMB;
    const float* wrow = w + o * (C_EMB * KERNEL_K) + k;
    float s = 0.f;
    #pragma unroll
    for (int i = 0; i < C_EMB; ++i)
        s += erow[i] * wrow[i * KERNEL_K];
    Th[c * T_ROW + k * CONV_L + o] = (_Float16)s;
}

// ---------------------------------------------------------------------------
// Fused main kernel. Blocks [0,WB): word-emb gather. Blocks [WB,WB+CB): char
// conv/maxpool. Char path: wave = 2 words (half-wave each), lane owns 8
// channels (half8 = 16 B loads, 512 B per half-wave per (c,k) row).
// The 16 chars are processed as 4 groups of 4 with two alternating register
// buffers -> up to 24 independent 16-B loads in flight per lane.
// All accumulation in packed fp16 (v_pk_add/max_f16); fp32 only at epilogue.
__global__ __launch_bounds__(256, 3)
void main_kernel(const int* __restrict__ X,
                 const int* __restrict__ Xw,
                 const _Float16* __restrict__ Th,
                 const float* __restrict__ conv_b,
                 const float* __restrict__ word_emb,
                 float* __restrict__ out,
                 int word_blocks, int char_blocks) {
    const int lane = threadIdx.x & 63;
    const int waveInBlock = threadIdx.x >> 6;

    if ((int)blockIdx.x < word_blocks) {
        const int wavesTotal = word_blocks * 4;
        const int waveId = blockIdx.x * 4 + waveInBlock;
        for (int n = waveId; n < N_WORDS; n += wavesTotal) {
            int widx = Xw[n];
            const float4* src = (const float4*)(word_emb + (size_t)widx * D_EMB);
            float4* dst = (float4*)(out + (size_t)n * OUT_STRIDE + CONV_L);
            dst[lane] = src[lane];
            if (lane < (D_EMB / 4 - 64)) {
                dst[64 + lane] = src[64 + lane];
            }
        }
    } else {
        const int wavesTotal = char_blocks * 4;
        const int waveId = ((int)blockIdx.x - word_blocks) * 4 + waveInBlock;
        const int sel = lane >> 5;
        const int l32 = lane & 31;   // owns channels [l32*8, l32*8+8)

        float bias[8];
        {
            float4 b0 = ((const float4*)(conv_b + l32 * 8))[0];
            float4 b1 = ((const float4*)(conv_b + l32 * 8))[1];
            bias[0]=b0.x; bias[1]=b0.y; bias[2]=b0.z; bias[3]=b0.w;
            bias[4]=b1.x; bias[5]=b1.y; bias[6]=b1.z; bias[7]=b1.w;
        }

        for (int p = waveId; p < N_WORDS / 2; p += wavesTotal) {
            const int n = p * 2 + sel;
            const int4* xr = (const int4*)(X + n * L_CHARS);
            int4 q0 = xr[0], q1 = xr[1], q2 = xr[2], q3 = xr[3];
            int cs[16] = {q0.x, q0.y, q0.z, q0.w,
                          q1.x, q1.y, q1.z, q1.w,
                          q2.x, q2.y, q2.z, q2.w,
                          q3.x, q3.y, q3.z, q3.w};

            half8 A[4][3], B[4][3];
            half8 a0 = (half8)(_Float16)0.f;
            half8 a1 = (half8)(_Float16)0.f;
            half8 m  = (half8)(_Float16)(-65504.f);

#define LOADG(BUF, G)                                                      \
            {                                                              \
                _Pragma("unroll")                                          \
                for (int jj = 0; jj < 4; ++jj) {                           \
                    const half8* Tc =                                      \
                        (const half8*)(Th + cs[(G) * 4 + jj] * T_ROW);     \
                    BUF[jj][0] = Tc[l32];                                  \
                    BUF[jj][1] = Tc[32 + l32];                             \
                    BUF[jj][2] = Tc[64 + l32];                             \
                }                                                          \
            }
#define COMPG(BUF)                                                         \
            {                                                              \
                _Pragma("unroll")                                          \
                for (int jj = 0; jj < 4; ++jj) {                           \
                    half8 yj = a0 + BUF[jj][2];                            \
                    m  = h8max(m, yj);                                     \
                    a0 = a1 + BUF[jj][1];                                  \
                    a1 = BUF[jj][0];                                       \
                }                                                          \
            }
            LOADG(A, 0);
            LOADG(B, 1);
            COMPG(A);
            LOADG(A, 2);
            COMPG(B);
            LOADG(B, 3);
            COMPG(A);
            COMPG(B);
#undef LOADG
#undef COMPG
            // tails: y[16] = a0, y[17] = a1
            m = h8max(m, a0);
            m = h8max(m, a1);

            float r[8];
            #pragma unroll
            for (int e = 0; e < 8; ++e)
                r[e] = fmaxf((float)m[e] + bias[e], 0.f);
            float4* dst = (float4*)(out + (size_t)n * OUT_STRIDE + l32 * 8);
            dst[0] = make_float4(r[0], r[1], r[2], r[3]);
            dst[1] = make_float4(r[4], r[5], r[6], r[7]);
        }
    }
}

extern "C" void kernel_launch(void* const* d_in, const int* in_sizes, int n_in,
                              void* d_out, int out_size, void* d_ws, size_t ws_size,
                              hipStream_t stream) {
    const int*   X    = (const int*)d_in[0];
    const int*   Xw   = (const int*)d_in[1];
    const float* emb  = (const float*)d_in[2];
    const float* w    = (const float*)d_in[3];
    const float* b    = (const float*)d_in[4];
    const float* we   = (const float*)d_in[5];
    float* out = (float*)d_out;

    _Float16* Th = (_Float16*)d_ws;   // 128*768*2 = 196608 B of workspace

    build_table<<<CHAR_SIZE * KERNEL_K, 256, 0, stream>>>(emb, w, Th);

    const int WB = 256;   // word-gather: 1024 waves, 16 words each
    const int CB = 1024;  // char path: 4096 waves, 2 word-pairs each
    main_kernel<<<WB + CB, 256, 0, stream>>>(X, Xw, Th, b, we, out, WB, CB);
}

// Round 4
// 133.341 us; speedup vs baseline: 1.1089x; 1.1089x over previous
//
#include <hip/hip_runtime.h>

#define N_WORDS   16384
#define L_CHARS   16
#define CHAR_SIZE 128
#define C_EMB     64
#define CONV_L    256
#define KERNEL_K  3
#define D_EMB     300
#define OUT_STRIDE (CONV_L + D_EMB)   // 556
#define CH_Q      64                  // channels per quarter-slice
#define SLICE_H   (CHAR_SIZE * KERNEL_K * CH_Q)   // 24576 halves = 48 KB

typedef _Float16 half8 __attribute__((ext_vector_type(8)));

static __device__ __forceinline__ half8 h8max(half8 a, half8 b) {
#if __has_builtin(__builtin_elementwise_max)
    return __builtin_elementwise_max(a, b);
#else
    half8 r;
    #pragma unroll
    for (int i = 0; i < 8; ++i) r[i] = a[i] > b[i] ? a[i] : b[i];
    return r;
#endif
}

// ---------------------------------------------------------------------------
// Kernel A (R2-proven): transpose conv_w (O,I,K) -> Wt (I,K,O). Coalesced
// reads; scattered writes (fine, 196 KB).
__global__ void transpose_w(const float* __restrict__ w, float* __restrict__ Wt) {
    int tid = blockIdx.x * blockDim.x + threadIdx.x;
    if (tid >= CONV_L * C_EMB * KERNEL_K) return;
    int o = tid / (C_EMB * KERNEL_K);
    int r = tid - o * (C_EMB * KERNEL_K);
    int i = r / KERNEL_K;
    int k = r - i * KERNEL_K;
    Wt[i * (KERNEL_K * CONV_L) + k * CONV_L + o] = w[tid];
}

// ---------------------------------------------------------------------------
// Kernel B: folded table, written in quarter-sliced layout:
//   Th[q][c][k][oi] = (half) sum_i emb[c][i] * Wt[i][k][q*64+oi]
// Block (c,k); thread o. Wt reads coalesced (1 KB/wave/iter, L2-resident).
__global__ void build_table(const float* __restrict__ emb,
                            const float* __restrict__ Wt,
                            _Float16* __restrict__ Th) {
    int c = blockIdx.x / 3;
    int k = blockIdx.x % 3;
    int o = threadIdx.x;
    const float* erow = emb + c * C_EMB;
    float s = 0.f;
    #pragma unroll
    for (int i = 0; i < C_EMB; ++i)
        s += erow[i] * Wt[i * (KERNEL_K * CONV_L) + k * CONV_L + o];
    int q  = o >> 6;
    int oi = o & 63;
    Th[q * SLICE_H + c * (KERNEL_K * CH_Q) + k * CH_Q + oi] = (_Float16)s;
}

// ---------------------------------------------------------------------------
// Kernel C (fused main).
// Blocks [0, WB): word-embedding gather (unchanged, no LDS).
// Blocks [WB, WB+CB): char conv/maxpool with the table slice staged in LDS.
//   CB = 1024 char blocks: q = cb&3 (channel quarter), wgrp = cb>>2 selects
//   64 words. Each block stages its contiguous 48 KB slice once (coalesced),
//   then 4 waves x 8-lane groups process 8 words/wave/pass, 2 passes.
//   Lane owns 8 channels -> half8 (16 B) ds_read per (char,k); uniform bank
//   coverage (each group's 8x16B spans all 32 banks).
__global__ __launch_bounds__(256, 3)
void main_kernel(const int* __restrict__ X,
                 const int* __restrict__ Xw,
                 const _Float16* __restrict__ Th,
                 const float* __restrict__ conv_b,
                 const float* __restrict__ word_emb,
                 float* __restrict__ out,
                 int word_blocks) {
    __shared__ __align__(16) _Float16 Ts[SLICE_H];   // 48 KB

    const int lane = threadIdx.x & 63;
    const int wv   = threadIdx.x >> 6;

    if ((int)blockIdx.x < word_blocks) {
        const int wavesTotal = word_blocks * 4;
        const int waveId = blockIdx.x * 4 + wv;
        for (int n = waveId; n < N_WORDS; n += wavesTotal) {
            int widx = Xw[n];
            const float4* src = (const float4*)(word_emb + (size_t)widx * D_EMB);
            float4* dst = (float4*)(out + (size_t)n * OUT_STRIDE + CONV_L);
            dst[lane] = src[lane];
            if (lane < (D_EMB / 4 - 64)) {
                dst[64 + lane] = src[64 + lane];
            }
        }
        return;
    }

    const int cb   = (int)blockIdx.x - word_blocks;   // 0..1023
    const int q    = cb & 3;                          // channel quarter
    const int wgrp = cb >> 2;                         // word group, 0..255

    // ---- stage the 48 KB slice (fully coalesced contiguous read) ----
    {
        const float4* src = (const float4*)(Th + q * SLICE_H);
        float4* dst = (float4*)Ts;
        #pragma unroll
        for (int i = 0; i < 12; ++i)
            dst[threadIdx.x + i * 256] = src[threadIdx.x + i * 256];
    }
    __syncthreads();

    const int g  = lane >> 3;   // word within the wave's 8
    const int l8 = lane & 7;    // owns channels q*64 + l8*8 .. +8

    float bias[8];
    {
        const float4* bp = (const float4*)(conv_b + q * CH_Q + l8 * 8);
        float4 b0 = bp[0], b1 = bp[1];
        bias[0]=b0.x; bias[1]=b0.y; bias[2]=b0.z; bias[3]=b0.w;
        bias[4]=b1.x; bias[5]=b1.y; bias[6]=b1.z; bias[7]=b1.w;
    }

    #pragma unroll
    for (int pass = 0; pass < 2; ++pass) {
        const int n = wgrp * 64 + pass * 32 + wv * 8 + g;

        // all 8 lanes of the group load the word's 16 chars (same 64 B row;
        // L1 broadcast)
        const int4* xr = (const int4*)(X + n * L_CHARS);
        int4 q0 = xr[0], q1 = xr[1], q2 = xr[2], q3 = xr[3];
        int cs[16] = {q0.x, q0.y, q0.z, q0.w,
                      q1.x, q1.y, q1.z, q1.w,
                      q2.x, q2.y, q2.z, q2.w,
                      q3.x, q3.y, q3.z, q3.w};

        half8 a0 = (half8)(_Float16)0.f;
        half8 a1 = (half8)(_Float16)0.f;
        half8 m  = (half8)(_Float16)(-65504.f);

        #pragma unroll
        for (int j = 0; j < L_CHARS; ++j) {
            const _Float16* row = Ts + cs[j] * (KERNEL_K * CH_Q) + l8 * 8;
            half8 t0 = *(const half8*)(row);            // k=0
            half8 t1 = *(const half8*)(row + CH_Q);     // k=1
            half8 t2 = *(const half8*)(row + 2*CH_Q);   // k=2
            half8 yj = a0 + t2;          // y[j] complete
            m  = h8max(m, yj);
            a0 = a1 + t1;                // partial y[j+1]
            a1 = t0;                     // partial y[j+2]
        }
        m = h8max(m, a0);   // y[16]
        m = h8max(m, a1);   // y[17]

        float r[8];
        #pragma unroll
        for (int e = 0; e < 8; ++e)
            r[e] = fmaxf((float)m[e] + bias[e], 0.f);
        float4* dst = (float4*)(out + (size_t)n * OUT_STRIDE + q * CH_Q + l8 * 8);
        dst[0] = make_float4(r[0], r[1], r[2], r[3]);
        dst[1] = make_float4(r[4], r[5], r[6], r[7]);
    }
}

extern "C" void kernel_launch(void* const* d_in, const int* in_sizes, int n_in,
                              void* d_out, int out_size, void* d_ws, size_t ws_size,
                              hipStream_t stream) {
    const int*   X    = (const int*)d_in[0];
    const int*   Xw   = (const int*)d_in[1];
    const float* emb  = (const float*)d_in[2];
    const float* w    = (const float*)d_in[3];
    const float* b    = (const float*)d_in[4];
    const float* we   = (const float*)d_in[5];
    float* out = (float*)d_out;

    // ws layout: Th (fp16, 196608 B) | Wt (fp32, 196608 B)
    _Float16* Th = (_Float16*)d_ws;
    float*    Wt = (float*)((char*)d_ws + 4 * SLICE_H * sizeof(_Float16));

    transpose_w<<<(CONV_L * C_EMB * KERNEL_K + 255) / 256, 256, 0, stream>>>(w, Wt);
    build_table<<<CHAR_SIZE * KERNEL_K, 256, 0, stream>>>(emb, Wt, Th);

    const int WB = 256;    // word-gather blocks
    const int CB = 1024;   // char blocks: 4 quarters x 256 word-groups
    main_kernel<<<WB + CB, 256, 0, stream>>>(X, Xw, Th, b, we, out, WB);
}